// Round 1
// baseline (3009.451 us; speedup 1.0000x reference)
//
#include <hip/hip_runtime.h>
#include <math.h>

// Problem constants
constexpr int CIN = 32, COUT = 64;
constexpr int D = 16, H = 32, W = 32;
// final out: [16,1,5,10,10] -> 8000 elements
// y window per out elem: 6^3 at base (6d0,6h0,6w0); x footprint 5^3 per cin.

// Padded transposed weights: WTP[cls][t][ci][co], cls in [0,8), t=td*9+th*3+tw in [0,27)
// kd = pd + 2*td (zero if >=5), etc.  8*27*32*64 floats = 1.77 MB.
__global__ void prep_weights(const float* __restrict__ w, float* __restrict__ wtp) {
    int idx = blockIdx.x * 256 + threadIdx.x;
    // total = 8*27*32*64 = 442368 = 1728*256 exactly
    int co  = idx & 63;
    int ci  = (idx >> 6) & 31;
    int t   = (idx >> 11) % 27;
    int cls = idx / (27 * 2048);
    int td = t / 9, th = (t / 3) % 3, tw = t % 3;
    int pd = (cls >> 2) & 1, ph = (cls >> 1) & 1, pw = cls & 1;
    int kd = pd + 2 * td, kh = ph + 2 * th, kw = pw + 2 * tw;
    float v = 0.f;
    if (kd < 5 && kh < 5 && kw < 5)
        v = w[((ci * COUT + co) * 125) + kd * 25 + kh * 5 + kw];
    wtp[idx] = v;
}

template <bool USE_WTP>
__global__ __launch_bounds__(256) void fused_kernel(
    const float* __restrict__ x, const float* __restrict__ wsrc,
    const float* __restrict__ bias, const float* __restrict__ wtp,
    float* __restrict__ out)
{
    __shared__ float xs[CIN * 125];   // [ci][5][5][5]
    __shared__ float wmax[4][64];

    const int b  = blockIdx.x;
    const int w0 = b % 10;
    const int h0 = (b / 10) % 10;
    const int d0 = (b / 100) % 5;
    const int n  = b / 500;
    const int tid = threadIdx.x;

    // ---- Stage x footprint into LDS (zero-filled at low edges) ----
    const int id0 = 3 * d0 - 1, ih0 = 3 * h0 - 1, iw0 = 3 * w0 - 1;
    for (int e = tid; e < CIN * 125; e += 256) {
        int kk = e % 5, jj = (e / 5) % 5, ii = (e / 25) % 5, c = e / 125;
        int id = id0 + ii, ih = ih0 + jj, iw = iw0 + kk;
        float v = 0.f;
        if (id >= 0 && ih >= 0 && iw >= 0)  // high side always in range for this grid
            v = x[(((n * CIN + c) * D + id) * H + ih) * W + iw];
        xs[e] = v;
    }
    __syncthreads();

    const int lane = tid & 63;   // = c_out
    const int wv   = tid >> 6;   // wave id 0..3 -> classes {2wv, 2wv+1}

    float lmax = -INFINITY;

    for (int ccls = 0; ccls < 2; ++ccls) {
        const int cls = wv * 2 + ccls;
        const float* wp = wtp + (size_t)cls * 27 * 2048;
        const int pd = (cls >> 2) & 1, ph = (cls >> 1) & 1, pw = cls & 1;

        float acc[27];
#pragma unroll
        for (int i = 0; i < 27; ++i) acc[i] = 0.f;

        for (int ci = 0; ci < CIN; ++ci) {
            // load 27 weights for this (cls, ci), lane = c_out (coalesced for WTP)
            float wr[27];
#pragma unroll
            for (int t = 0; t < 27; ++t) {
                if (USE_WTP) {
                    wr[t] = wp[(t * CIN + ci) * 64 + lane];
                } else {
                    int td = t / 9, th = (t / 3) % 3, tw = t % 3;
                    int kd = pd + 2 * td, kh = ph + 2 * th, kw = pw + 2 * tw;
                    wr[t] = (kd < 5 && kh < 5 && kw < 5)
                              ? wsrc[((ci * 64 + lane) * 125) + kd * 25 + kh * 5 + kw]
                              : 0.f;
                }
            }
            const float* xb = xs + ci * 125;
#pragma unroll
            for (int td = 0; td < 3; ++td)
#pragma unroll
            for (int th = 0; th < 3; ++th)
#pragma unroll
            for (int tw = 0; tw < 3; ++tw) {
                const float wval = wr[(td * 3 + th) * 3 + tw];
#pragma unroll
                for (int a = 0; a < 3; ++a)
#pragma unroll
                for (int bb = 0; bb < 3; ++bb)
#pragma unroll
                for (int cc = 0; cc < 3; ++cc) {
                    // local x index: (a+2-td, bb+2-th, cc+2-tw), all in [0,4]
                    acc[(a * 3 + bb) * 3 + cc] +=
                        xb[(a + 2 - td) * 25 + (bb + 2 - th) * 5 + (cc + 2 - tw)] * wval;
                }
            }
        }
#pragma unroll
        for (int i = 0; i < 27; ++i) lmax = fmaxf(lmax, acc[i]);
    }

    wmax[wv][lane] = lmax;
    __syncthreads();

    if (wv == 0) {
        float m = fmaxf(fmaxf(wmax[0][lane], wmax[1][lane]),
                        fmaxf(wmax[2][lane], wmax[3][lane]));
        m += bias[lane];  // bias is constant per channel: max(y) = bias + max(conv)
        for (int off = 32; off > 0; off >>= 1)
            m += __shfl_down(m, off);
        if (lane == 0) out[b] = m;
    }
}

extern "C" void kernel_launch(void* const* d_in, const int* in_sizes, int n_in,
                              void* d_out, int out_size, void* d_ws, size_t ws_size,
                              hipStream_t stream) {
    const float* x    = (const float*)d_in[0];
    const float* w    = (const float*)d_in[1];
    const float* bias = (const float*)d_in[2];
    float* out = (float*)d_out;

    const size_t wtp_bytes = (size_t)8 * 27 * 32 * 64 * sizeof(float);
    if (ws_size >= wtp_bytes) {
        float* wtp = (float*)d_ws;
        prep_weights<<<1728, 256, 0, stream>>>(w, wtp);
        fused_kernel<true><<<8000, 256, 0, stream>>>(x, w, bias, wtp, out);
    } else {
        fused_kernel<false><<<8000, 256, 0, stream>>>(x, w, bias, nullptr, out);
    }
}

// Round 2
// 426.519 us; speedup vs baseline: 7.0558x; 7.0558x over previous
//
#include <hip/hip_runtime.h>
#include <hip/hip_bf16.h>
#include <math.h>

typedef short bf16x8 __attribute__((ext_vector_type(8)));
typedef float f32x4 __attribute__((ext_vector_type(4)));

constexpr int CIN = 32, COUT = 64, D = 16, H = 32, W = 32;

// ---------------- ws layout ----------------
// [0, 884736)                     : wtp bf16 [cls8][t27][co64][ci32]
// [1MB, 1MB+33554432)             : xT  bf16 [n16][id16][ih32][iw32][ci32]
// [1MB+33554432, +16384000)       : partial f32 [cls8][elem8000][co64]
constexpr size_t WS_XT_OFF   = 1u << 20;
constexpr size_t WS_PART_OFF = WS_XT_OFF + 33554432u;
constexpr size_t WS_NEED     = WS_PART_OFF + 16384000u;

// Pack weights: wtp[cls][t][co][ci] = w[ci][co][kd][kh][kw], kd=pd+2td etc (0 if k>=5)
__global__ void prep_w(const float* __restrict__ w, unsigned short* __restrict__ wtp) {
    int idx = blockIdx.x * 256 + threadIdx.x;            // 442368 total
    int ci  = idx & 31;
    int co  = (idx >> 5) & 63;
    int tt  = idx >> 11;                                  // cls*27 + t
    int t   = tt % 27, cls = tt / 27;
    int td = t / 9, th = (t / 3) % 3, tw = t % 3;
    int pd = (cls >> 2) & 1, ph = (cls >> 1) & 1, pw = cls & 1;
    int kd = pd + 2 * td, kh = ph + 2 * th, kw = pw + 2 * tw;
    float v = 0.f;
    if (kd < 5 && kh < 5 && kw < 5)
        v = w[(ci * COUT + co) * 125 + kd * 25 + kh * 5 + kw];
    __hip_bfloat16 b = __float2bfloat16(v);
    wtp[idx] = *reinterpret_cast<unsigned short*>(&b);
}

// x [n][ci][id][ih][iw] fp32 -> xT [n][id][ih][iw][ci] bf16
__global__ void transpose_x(const float* __restrict__ x, unsigned short* __restrict__ xT) {
    __shared__ float tile[32 * 33];
    int bid = blockIdx.x;                    // n*512 + id*32 + ih
    int ih = bid & 31, id = (bid >> 5) & 15, n = bid >> 9;
    int tid = threadIdx.x;
    int lw = tid & 31, g = tid >> 5;         // g in [0,8)
#pragma unroll
    for (int p = 0; p < 4; ++p) {
        int ci = g + p * 8;
        tile[lw * 33 + ci] = x[((((size_t)n * CIN + ci) * D + id) * H + ih) * W + lw];
    }
    __syncthreads();
    unsigned short* op = xT + ((((size_t)n * D + id) * H + ih) * W) * CIN;
#pragma unroll
    for (int p = 0; p < 4; ++p) {
        int iw = g + p * 8;
        __hip_bfloat16 b = __float2bfloat16(tile[iw * 33 + lw]);
        op[iw * 32 + lw] = *reinterpret_cast<unsigned short*>(&b);
    }
}

template <int NW>
__device__ __forceinline__ void do_compute(
    const unsigned short* __restrict__ Bs, const unsigned short* __restrict__ Xs,
    const int (&S0)[3][2], int ci0, int l15,
    int ntd, int nth, int ntw, float (&omax)[3][4])
{
    f32x4 acc[NW][2][4];
#pragma unroll
    for (int w = 0; w < NW; ++w)
#pragma unroll
        for (int mt = 0; mt < 2; ++mt)
#pragma unroll
            for (int nt = 0; nt < 4; ++nt) acc[w][mt][nt] = (f32x4){0.f, 0.f, 0.f, 0.f};

    for (int td = 0; td < ntd; ++td)
    for (int th = 0; th < nth; ++th)
    for (int tw = 0; tw < ntw; ++tw) {
        int t  = td * 9 + th * 3 + tw;
        int dt = td * 160 + th * 32 + tw;
        const unsigned short* bp = Bs + (t * 64 + l15) * 32 + ci0;
        bf16x8 bf0 = *(const bf16x8*)(bp);
        bf16x8 bf1 = *(const bf16x8*)(bp + 512);
        bf16x8 bf2 = *(const bf16x8*)(bp + 1024);
        bf16x8 bf3 = *(const bf16x8*)(bp + 1536);
#pragma unroll
        for (int w = 0; w < NW; ++w) {
#pragma unroll
            for (int mt = 0; mt < 2; ++mt) {
                bf16x8 af = *(const bf16x8*)(Xs + (S0[w][mt] - dt) * 32 + ci0);
                acc[w][mt][0] = __builtin_amdgcn_mfma_f32_16x16x32_bf16(af, bf0, acc[w][mt][0], 0, 0, 0);
                acc[w][mt][1] = __builtin_amdgcn_mfma_f32_16x16x32_bf16(af, bf1, acc[w][mt][1], 0, 0, 0);
                acc[w][mt][2] = __builtin_amdgcn_mfma_f32_16x16x32_bf16(af, bf2, acc[w][mt][2], 0, 0, 0);
                acc[w][mt][3] = __builtin_amdgcn_mfma_f32_16x16x32_bf16(af, bf3, acc[w][mt][3], 0, 0, 0);
            }
        }
    }
#pragma unroll
    for (int w = 0; w < NW; ++w)
#pragma unroll
        for (int nt = 0; nt < 4; ++nt) {
            float m = acc[w][0][nt][0];
            m = fmaxf(m, acc[w][0][nt][1]);
            m = fmaxf(m, acc[w][0][nt][2]);
            m = fmaxf(m, acc[w][0][nt][3]);
            m = fmaxf(m, acc[w][1][nt][0]);
            m = fmaxf(m, acc[w][1][nt][1]);
            m = fmaxf(m, acc[w][1][nt][2]);
            m = fmaxf(m, acc[w][1][nt][3]);
            m = fmaxf(m, __shfl_xor(m, 16));
            m = fmaxf(m, __shfl_xor(m, 32));
            omax[w][nt] = m;
        }
}

__global__ __launch_bounds__(256) void main_k(
    const unsigned short* __restrict__ wtp, const unsigned short* __restrict__ xT,
    float* __restrict__ partial)
{
    __shared__ unsigned short Bs[27 * 64 * 32];   // 110592 B
    __shared__ unsigned short Xs[5 * 5 * 32 * 32]; //  51200 B
    int bx  = blockIdx.x;                          // n*80 + d0*16 + hh*8 + cls
    int cls = bx & 7;
    int hh  = (bx >> 3) & 1;
    int d0  = (bx >> 4) % 5;
    int n   = bx / 80;
    int pd = (cls >> 2) & 1, ph = (cls >> 1) & 1, pw = cls & 1;
    int ntd = 3 - pd, nth = 3 - ph, ntw = 3 - pw;
    int tid = threadIdx.x;

    // stage B_cls (once per block)
    {
        const float4* wsrc = (const float4*)wtp + (size_t)cls * 6912;
        float4* bdst = (float4*)Bs;
        for (int i = tid; i < 6912; i += 256) bdst[i] = wsrc[i];
    }

    int lane = tid & 63, wv = tid >> 6;
    int l15 = lane & 15, quad = lane >> 4, ci0 = quad * 8;
    const int starts[4] = {0, 3, 6, 8};
    const int cnts[4]   = {3, 3, 2, 2};
    int id0 = 3 * d0 - 1;

    for (int j = 0; j < 5; ++j) {
        int h0  = hh * 5 + j;
        int ih0 = 3 * h0 - 1;
        __syncthreads();   // protect Xs (prev readers) / Bs (first iter)
        for (int i = tid; i < 3200; i += 256) {
            int cb = i & 3, ww = (i >> 2) & 31, hl = (i >> 7) % 5, dd = i / 640;
            int id = id0 + dd, ih = ih0 + hl, iw = ww - 1;
            float4 v = {0.f, 0.f, 0.f, 0.f};
            if (id >= 0 && ih >= 0 && iw >= 0)
                v = ((const float4*)(xT + ((((size_t)n * D + id) * H + ih) * W + iw) * 32))[cb];
            ((float4*)Xs)[i] = v;
        }
        __syncthreads();

        int widx = (wv + j) & 3;
        int wst = starts[widx], wcnt = cnts[widx];
        int S0[3][2];
#pragma unroll
        for (int w = 0; w < 3; ++w)
#pragma unroll
            for (int mt = 0; mt < 2; ++mt) {
                int row = mt * 16 + l15;
                int pos = row < 27 ? row : 26;
                int a = pos / 9, b = (pos / 3) % 3, c = pos % 3;
                int w0 = (w < wcnt) ? (wst + w) : wst;
                S0[w][mt] = ((2 + a) * 5 + (2 + b)) * 32 + (3 * w0 + 2 + c);
            }

        float omax[3][4];
        if (wcnt == 3) do_compute<3>(Bs, Xs, S0, ci0, l15, ntd, nth, ntw, omax);
        else           do_compute<2>(Bs, Xs, S0, ci0, l15, ntd, nth, ntw, omax);

        int elemBase = ((n * 5 + d0) * 10 + h0) * 10;
        if (quad == 0) {
            for (int w = 0; w < wcnt; ++w) {
                int elem = elemBase + wst + w;
                float* pp = partial + ((size_t)(cls * 8000 + elem)) * 64;
#pragma unroll
                for (int nt = 0; nt < 4; ++nt) pp[nt * 16 + l15] = omax[w][nt];
            }
        }
    }
}

__global__ void finalize_k(const float* __restrict__ partial, const float* __restrict__ bias,
                           float* __restrict__ out)
{
    int tid = threadIdx.x;
    int el  = blockIdx.x * 4 + (tid >> 6);   // 2000 blocks, wave per elem
    int co  = tid & 63;
    float m = -INFINITY;
#pragma unroll
    for (int cls = 0; cls < 8; ++cls)
        m = fmaxf(m, partial[((size_t)(cls * 8000 + el)) * 64 + co]);
    float v = m + bias[co];
#pragma unroll
    for (int off = 32; off > 0; off >>= 1) v += __shfl_xor(v, off);
    if (co == 0) out[el] = v;
}

// ---------------- fallback (round-1 kernel, no ws needed) ----------------
__global__ __launch_bounds__(256) void fused_fallback(
    const float* __restrict__ x, const float* __restrict__ wsrc,
    const float* __restrict__ bias, float* __restrict__ out)
{
    __shared__ float xs[CIN * 125];
    __shared__ float wmax[4][64];
    const int b  = blockIdx.x;
    const int w0 = b % 10, h0 = (b / 10) % 10, d0 = (b / 100) % 5, n = b / 500;
    const int tid = threadIdx.x;
    const int id0 = 3 * d0 - 1, ih0 = 3 * h0 - 1, iw0 = 3 * w0 - 1;
    for (int e = tid; e < CIN * 125; e += 256) {
        int kk = e % 5, jj = (e / 5) % 5, ii = (e / 25) % 5, c = e / 125;
        int id = id0 + ii, ih = ih0 + jj, iw = iw0 + kk;
        float v = 0.f;
        if (id >= 0 && ih >= 0 && iw >= 0)
            v = x[(((n * CIN + c) * D + id) * H + ih) * W + iw];
        xs[e] = v;
    }
    __syncthreads();
    const int lane = tid & 63, wv = tid >> 6;
    float lmax = -INFINITY;
    for (int ccls = 0; ccls < 2; ++ccls) {
        const int cls = wv * 2 + ccls;
        const int pd = (cls >> 2) & 1, ph = (cls >> 1) & 1, pw = cls & 1;
        float acc[27];
#pragma unroll
        for (int i = 0; i < 27; ++i) acc[i] = 0.f;
        for (int ci = 0; ci < CIN; ++ci) {
            float wr[27];
#pragma unroll
            for (int t = 0; t < 27; ++t) {
                int td = t / 9, th = (t / 3) % 3, tw = t % 3;
                int kd = pd + 2 * td, kh = ph + 2 * th, kw = pw + 2 * tw;
                wr[t] = (kd < 5 && kh < 5 && kw < 5)
                          ? wsrc[((ci * 64 + lane) * 125) + kd * 25 + kh * 5 + kw] : 0.f;
            }
            const float* xb = xs + ci * 125;
#pragma unroll
            for (int td = 0; td < 3; ++td)
#pragma unroll
            for (int th = 0; th < 3; ++th)
#pragma unroll
            for (int tw = 0; tw < 3; ++tw) {
                const float wval = wr[(td * 3 + th) * 3 + tw];
#pragma unroll
                for (int a = 0; a < 3; ++a)
#pragma unroll
                for (int bb = 0; bb < 3; ++bb)
#pragma unroll
                for (int cc = 0; cc < 3; ++cc)
                    acc[(a * 3 + bb) * 3 + cc] +=
                        xb[(a + 2 - td) * 25 + (bb + 2 - th) * 5 + (cc + 2 - tw)] * wval;
            }
        }
#pragma unroll
        for (int i = 0; i < 27; ++i) lmax = fmaxf(lmax, acc[i]);
    }
    wmax[wv][lane] = lmax;
    __syncthreads();
    if (wv == 0) {
        float m = fmaxf(fmaxf(wmax[0][lane], wmax[1][lane]),
                        fmaxf(wmax[2][lane], wmax[3][lane]));
        m += bias[lane];
        for (int off = 32; off > 0; off >>= 1) m += __shfl_down(m, off);
        if (lane == 0) out[b] = m;
    }
}

extern "C" void kernel_launch(void* const* d_in, const int* in_sizes, int n_in,
                              void* d_out, int out_size, void* d_ws, size_t ws_size,
                              hipStream_t stream) {
    const float* x    = (const float*)d_in[0];
    const float* w    = (const float*)d_in[1];
    const float* bias = (const float*)d_in[2];
    float* out = (float*)d_out;

    if (ws_size >= WS_NEED) {
        unsigned short* wtp = (unsigned short*)d_ws;
        unsigned short* xT  = (unsigned short*)((char*)d_ws + WS_XT_OFF);
        float* partial      = (float*)((char*)d_ws + WS_PART_OFF);
        prep_w<<<1728, 256, 0, stream>>>(w, wtp);
        transpose_x<<<8192, 256, 0, stream>>>(x, xT);
        main_k<<<1280, 256, 0, stream>>>(wtp, xT, partial);
        finalize_k<<<2000, 256, 0, stream>>>(partial, bias, out);
    } else {
        fused_fallback<<<8000, 256, 0, stream>>>(x, w, bias, out);
    }
}

// Round 3
// 284.638 us; speedup vs baseline: 10.5729x; 1.4985x over previous
//
#include <hip/hip_runtime.h>
#include <hip/hip_bf16.h>
#include <math.h>

typedef short bf16x8 __attribute__((ext_vector_type(8)));
typedef float f32x4 __attribute__((ext_vector_type(4)));

constexpr int CIN = 32, COUT = 64, D = 16, H = 32, W = 32;

// ---------------- ws layout ----------------
// [0, 884736)                     : wtp bf16 [cls8][t27][co64][ci32]
// [1MB, 1MB+33554432)             : xT  bf16 [n16][id16][ih32][iw32][ci32]
// [1MB+33554432, +16384000)       : partial f32 [cls8][elem8000][co64]
constexpr size_t WS_XT_OFF   = 1u << 20;
constexpr size_t WS_PART_OFF = WS_XT_OFF + 33554432u;
constexpr size_t WS_NEED     = WS_PART_OFF + 16384000u;

__global__ void prep_w(const float* __restrict__ w, unsigned short* __restrict__ wtp) {
    int idx = blockIdx.x * 256 + threadIdx.x;            // 442368 total
    int ci  = idx & 31;
    int co  = (idx >> 5) & 63;
    int tt  = idx >> 11;                                  // cls*27 + t
    int t   = tt % 27, cls = tt / 27;
    int td = t / 9, th = (t / 3) % 3, tw = t % 3;
    int pd = (cls >> 2) & 1, ph = (cls >> 1) & 1, pw = cls & 1;
    int kd = pd + 2 * td, kh = ph + 2 * th, kw = pw + 2 * tw;
    float v = 0.f;
    if (kd < 5 && kh < 5 && kw < 5)
        v = w[(ci * COUT + co) * 125 + kd * 25 + kh * 5 + kw];
    __hip_bfloat16 b = __float2bfloat16(v);
    wtp[idx] = *reinterpret_cast<unsigned short*>(&b);
}

// x [n][ci][id][ih][iw] fp32 -> xT [n][id][ih][iw][ci] bf16
__global__ void transpose_x(const float* __restrict__ x, unsigned short* __restrict__ xT) {
    __shared__ float tile[32 * 33];
    int bid = blockIdx.x;                    // n*512 + id*32 + ih
    int ih = bid & 31, id = (bid >> 5) & 15, n = bid >> 9;
    int tid = threadIdx.x;
    int lw = tid & 31, g = tid >> 5;         // g in [0,8)
#pragma unroll
    for (int p = 0; p < 4; ++p) {
        int ci = g + p * 8;
        tile[lw * 33 + ci] = x[((((size_t)n * CIN + ci) * D + id) * H + ih) * W + lw];
    }
    __syncthreads();
    unsigned short* op = xT + ((((size_t)n * D + id) * H + ih) * W) * CIN;
#pragma unroll
    for (int p = 0; p < 4; ++p) {
        int iw = g + p * 8;
        __hip_bfloat16 b = __float2bfloat16(tile[iw * 33 + lw]);
        op[iw * 32 + lw] = *reinterpret_cast<unsigned short*>(&b);
    }
}

// Xs swizzled layout: logical (dd,hl,ww,ci) -> row R=(dd*5+hl)*32+ww (32 elems),
// 16B-granule g=ci>>3 stored at phys granule g ^ ((dd+hl+ww)&3).
template <int NW>
__device__ __forceinline__ void do_compute(
    const unsigned short* __restrict__ wp, const unsigned short* __restrict__ Xs,
    const int (&R0)[3][2], const int (&s0)[3][2], int quad, int ci0, int l15,
    int ntd, int nth, int ntw, float (&omax)[3][4])
{
    f32x4 acc[NW][2][4];
#pragma unroll
    for (int w = 0; w < NW; ++w)
#pragma unroll
        for (int mt = 0; mt < 2; ++mt)
#pragma unroll
            for (int nt = 0; nt < 4; ++nt) acc[w][mt][nt] = (f32x4){0.f, 0.f, 0.f, 0.f};

    for (int td = 0; td < ntd; ++td)
    for (int th = 0; th < nth; ++th)
    for (int tw = 0; tw < ntw; ++tw) {
        const int t   = td * 9 + th * 3 + tw;
        const int dtR = td * 160 + th * 32 + tw;
        const int dts = td + th + tw;
        const unsigned short* bp = wp + (t * 64 + l15) * 32 + ci0;
        bf16x8 bf0 = *(const bf16x8*)(bp);
        bf16x8 bf1 = *(const bf16x8*)(bp + 512);
        bf16x8 bf2 = *(const bf16x8*)(bp + 1024);
        bf16x8 bf3 = *(const bf16x8*)(bp + 1536);
#pragma unroll
        for (int w = 0; w < NW; ++w) {
#pragma unroll
            for (int mt = 0; mt < 2; ++mt) {
                int s = (s0[w][mt] - dts) & 3;
                bf16x8 af = *(const bf16x8*)(Xs + (R0[w][mt] - dtR) * 32 + ((quad ^ s) << 3));
                acc[w][mt][0] = __builtin_amdgcn_mfma_f32_16x16x32_bf16(af, bf0, acc[w][mt][0], 0, 0, 0);
                acc[w][mt][1] = __builtin_amdgcn_mfma_f32_16x16x32_bf16(af, bf1, acc[w][mt][1], 0, 0, 0);
                acc[w][mt][2] = __builtin_amdgcn_mfma_f32_16x16x32_bf16(af, bf2, acc[w][mt][2], 0, 0, 0);
                acc[w][mt][3] = __builtin_amdgcn_mfma_f32_16x16x32_bf16(af, bf3, acc[w][mt][3], 0, 0, 0);
            }
        }
    }
#pragma unroll
    for (int w = 0; w < NW; ++w)
#pragma unroll
        for (int nt = 0; nt < 4; ++nt) {
            float m = acc[w][0][nt][0];
            m = fmaxf(m, acc[w][0][nt][1]);
            m = fmaxf(m, acc[w][0][nt][2]);
            m = fmaxf(m, acc[w][0][nt][3]);
            m = fmaxf(m, acc[w][1][nt][0]);
            m = fmaxf(m, acc[w][1][nt][1]);
            m = fmaxf(m, acc[w][1][nt][2]);
            m = fmaxf(m, acc[w][1][nt][3]);
            m = fmaxf(m, __shfl_xor(m, 16));
            m = fmaxf(m, __shfl_xor(m, 32));
            omax[w][nt] = m;
        }
}

__global__ __launch_bounds__(256, 3) void main_k(
    const unsigned short* __restrict__ wtp, const unsigned short* __restrict__ xT,
    float* __restrict__ partial)
{
    __shared__ unsigned short Xs[25600];           // 51200 B, swizzled
    int bx  = blockIdx.x;                          // ((n*5+d0)*10+h0)*8 + cls
    int cls = bx & 7;
    int h0  = (bx >> 3) % 10;
    int d0  = (bx / 80) % 5;
    int n   = bx / 400;
    int pd = (cls >> 2) & 1, ph = (cls >> 1) & 1, pw = cls & 1;
    int ntd = 3 - pd, nth = 3 - ph, ntw = 3 - pw;
    int tid = threadIdx.x;

    // ---- stage Xs (swizzled) ----
    int id0 = 3 * d0 - 1, ih0 = 3 * h0 - 1;
    for (int i = tid; i < 3200; i += 256) {
        int cb = i & 3, ww = (i >> 2) & 31, hl = (i >> 7) % 5, dd = i / 640;
        int id = id0 + dd, ih = ih0 + hl, iw = ww - 1;
        float4 v = {0.f, 0.f, 0.f, 0.f};
        if (id >= 0 && ih >= 0 && iw >= 0)
            v = ((const float4*)(xT + ((((size_t)n * D + id) * H + ih) * W + iw) * 32))[cb];
        int R = (dd * 5 + hl) * 32 + ww;
        ((float4*)Xs)[R * 4 + (cb ^ ((dd + hl + ww) & 3))] = v;
    }
    __syncthreads();

    int lane = tid & 63, wv = tid >> 6;
    int l15 = lane & 15, quad = lane >> 4, ci0 = quad * 8;
    const int starts[4] = {0, 3, 6, 8};
    const int cnts[4]   = {3, 3, 2, 2};
    int widx = (wv + h0) & 3;
    int wst = starts[widx], wcnt = cnts[widx];

    int R0[3][2], s0[3][2];
#pragma unroll
    for (int w = 0; w < 3; ++w)
#pragma unroll
        for (int mt = 0; mt < 2; ++mt) {
            int row = mt * 16 + l15;
            int pos = row < 27 ? row : 26;
            int a = pos / 9, b = (pos / 3) % 3, c = pos % 3;
            int w0v = (w < wcnt) ? (wst + w) : wst;
            R0[w][mt] = ((2 + a) * 5 + (2 + b)) * 32 + (3 * w0v + 2 + c);
            s0[w][mt] = a + b + c + 6 + 3 * w0v;   // >= max dts (6), so (s0-dts) >= 0
        }

    const unsigned short* wp = wtp + (size_t)cls * 27 * 2048;
    float omax[3][4];
    if (wcnt == 3) do_compute<3>(wp, Xs, R0, s0, quad, ci0, l15, ntd, nth, ntw, omax);
    else           do_compute<2>(wp, Xs, R0, s0, quad, ci0, l15, ntd, nth, ntw, omax);

    if (quad == 0) {
        int elemBase = ((n * 5 + d0) * 10 + h0) * 10;
        for (int w = 0; w < wcnt; ++w) {
            int elem = elemBase + wst + w;
            float* pp = partial + ((size_t)(cls * 8000 + elem)) * 64;
#pragma unroll
            for (int nt = 0; nt < 4; ++nt) pp[nt * 16 + l15] = omax[w][nt];
        }
    }
}

__global__ void finalize_k(const float* __restrict__ partial, const float* __restrict__ bias,
                           float* __restrict__ out)
{
    int tid = threadIdx.x;
    int el  = blockIdx.x * 4 + (tid >> 6);   // 2000 blocks, wave per elem
    int co  = tid & 63;
    float m = -INFINITY;
#pragma unroll
    for (int cls = 0; cls < 8; ++cls)
        m = fmaxf(m, partial[((size_t)(cls * 8000 + el)) * 64 + co]);
    float v = m + bias[co];
#pragma unroll
    for (int off = 32; off > 0; off >>= 1) v += __shfl_xor(v, off);
    if (co == 0) out[el] = v;
}

// ---------------- fallback (round-1 kernel, no ws needed) ----------------
__global__ __launch_bounds__(256) void fused_fallback(
    const float* __restrict__ x, const float* __restrict__ wsrc,
    const float* __restrict__ bias, float* __restrict__ out)
{
    __shared__ float xs[CIN * 125];
    __shared__ float wmax[4][64];
    const int b  = blockIdx.x;
    const int w0 = b % 10, h0 = (b / 10) % 10, d0 = (b / 100) % 5, n = b / 500;
    const int tid = threadIdx.x;
    const int id0 = 3 * d0 - 1, ih0 = 3 * h0 - 1, iw0 = 3 * w0 - 1;
    for (int e = tid; e < CIN * 125; e += 256) {
        int kk = e % 5, jj = (e / 5) % 5, ii = (e / 25) % 5, c = e / 125;
        int id = id0 + ii, ih = ih0 + jj, iw = iw0 + kk;
        float v = 0.f;
        if (id >= 0 && ih >= 0 && iw >= 0)
            v = x[(((n * CIN + c) * D + id) * H + ih) * W + iw];
        xs[e] = v;
    }
    __syncthreads();
    const int lane = tid & 63, wv = tid >> 6;
    float lmax = -INFINITY;
    for (int ccls = 0; ccls < 2; ++ccls) {
        const int cls = wv * 2 + ccls;
        const int pd = (cls >> 2) & 1, ph = (cls >> 1) & 1, pw = cls & 1;
        float acc[27];
#pragma unroll
        for (int i = 0; i < 27; ++i) acc[i] = 0.f;
        for (int ci = 0; ci < CIN; ++ci) {
            float wr[27];
#pragma unroll
            for (int t = 0; t < 27; ++t) {
                int td = t / 9, th = (t / 3) % 3, tw = t % 3;
                int kd = pd + 2 * td, kh = ph + 2 * th, kw = pw + 2 * tw;
                wr[t] = (kd < 5 && kh < 5 && kw < 5)
                          ? wsrc[((ci * 64 + lane) * 125) + kd * 25 + kh * 5 + kw] : 0.f;
            }
            const float* xb = xs + ci * 125;
#pragma unroll
            for (int td = 0; td < 3; ++td)
#pragma unroll
            for (int th = 0; th < 3; ++th)
#pragma unroll
            for (int tw = 0; tw < 3; ++tw) {
                const float wval = wr[(td * 3 + th) * 3 + tw];
#pragma unroll
                for (int a = 0; a < 3; ++a)
#pragma unroll
                for (int bb = 0; bb < 3; ++bb)
#pragma unroll
                for (int cc = 0; cc < 3; ++cc)
                    acc[(a * 3 + bb) * 3 + cc] +=
                        xb[(a + 2 - td) * 25 + (bb + 2 - th) * 5 + (cc + 2 - tw)] * wval;
            }
        }
#pragma unroll
        for (int i = 0; i < 27; ++i) lmax = fmaxf(lmax, acc[i]);
    }
    wmax[wv][lane] = lmax;
    __syncthreads();
    if (wv == 0) {
        float m = fmaxf(fmaxf(wmax[0][lane], wmax[1][lane]),
                        fmaxf(wmax[2][lane], wmax[3][lane]));
        m += bias[lane];
        for (int off = 32; off > 0; off >>= 1) m += __shfl_down(m, off);
        if (lane == 0) out[b] = m;
    }
}

extern "C" void kernel_launch(void* const* d_in, const int* in_sizes, int n_in,
                              void* d_out, int out_size, void* d_ws, size_t ws_size,
                              hipStream_t stream) {
    const float* x    = (const float*)d_in[0];
    const float* w    = (const float*)d_in[1];
    const float* bias = (const float*)d_in[2];
    float* out = (float*)d_out;

    if (ws_size >= WS_NEED) {
        unsigned short* wtp = (unsigned short*)d_ws;
        unsigned short* xT  = (unsigned short*)((char*)d_ws + WS_XT_OFF);
        float* partial      = (float*)((char*)d_ws + WS_PART_OFF);
        prep_w<<<1728, 256, 0, stream>>>(w, wtp);
        transpose_x<<<8192, 256, 0, stream>>>(x, xT);
        main_k<<<6400, 256, 0, stream>>>(wtp, xT, partial);
        finalize_k<<<2000, 256, 0, stream>>>(partial, bias, out);
    } else {
        fused_fallback<<<8000, 256, 0, stream>>>(x, w, bias, out);
    }
}